// Round 15
// baseline (224.742 us; speedup 1.0000x reference)
//
#include <hip/hip_runtime.h>
#include <hip/hip_bf16.h>

#define N_NODES 100000
#define R_REL 4
#define E_EDGES 160000
#define D 128
#define NEG_SLOPE 0.2f
#define CAPR 16    // per-(relation,dst) segment capacity; Poisson(1.6): P(>16)~1e-14
#define NB_DST 16  // dsts per k_aggproj block (100000/16 = 6250 blocks exactly)

typedef unsigned short u16x8 __attribute__((ext_vector_type(8)));
typedef unsigned short u16x4 __attribute__((ext_vector_type(4)));
typedef __bf16 bf16x8v __attribute__((ext_vector_type(8)));
typedef float f32x4 __attribute__((ext_vector_type(4)));

__device__ inline unsigned short f2bf(float f) {
    unsigned u = __float_as_uint(f);
    return (unsigned short)((u + 0x7FFFu + ((u >> 16) & 1u)) >> 16);
}
__device__ inline float bf2f(unsigned short h) {
    return __uint_as_float(((unsigned)h) << 16);
}

// fused setup: block 0 = prep (wl/wr/btot), blocks 1-32 = W transpose+cast,
// blocks 33..814 = zero cnt4 (4*N counters).
__global__ __launch_bounds__(512) void k_prep2(const float* __restrict__ Wsrc,
        const float* __restrict__ Wdst, const float* __restrict__ al,
        const float* __restrict__ ar, const float* __restrict__ gb,
        const float* __restrict__ hb, float* __restrict__ wl,
        float* __restrict__ wr, float* __restrict__ btot,
        unsigned short* __restrict__ Wt, unsigned* __restrict__ cnt4) {
    int b = blockIdx.x, t = threadIdx.x;
    if (b == 0) {
        int r = t >> 7, d = t & 127;
        const float* as = al + r * D;
        const float* ad = ar + r * D;
        const float* rs = Wsrc + (r * D + d) * D;
        const float* rd = Wdst + (r * D + d) * D;
        float s0 = 0.f, s1 = 0.f;
        for (int e = 0; e < D; e++) { s0 += rs[e] * as[e]; s1 += rd[e] * ad[e]; }
        wl[r * D + d] = s0; wr[r * D + d] = s1;
        if (t < D) {
            float bb = hb[t];
            for (int r2 = 0; r2 < R_REL; r2++) bb += gb[r2 * D + t];
            btot[t] = bb;
        }
    } else if (b <= 32) {
        int base = (b - 1) * 2048 + t;
        #pragma unroll
        for (int i = 0; i < 4; i++) {
            int idx = base + i * 512;
            int r = idx >> 14; int rem = idx & 16383; int e = rem >> 7; int k = rem & 127;
            Wt[idx] = f2bf(Wsrc[(r * D + k) * D + e]);
        }
    } else {
        int i = (b - 33) * 512 + t;
        if (i < R_REL * N_NODES) cnt4[i] = 0u;
    }
}

// fused: coalesced read of x (wave covers 2 rows), emits xb (bf16 cast),
// el[r,n] = x[n]·wl[r], er[r,n] = x[n]·wr[r] via shuffle reduce
__global__ __launch_bounds__(256) void k_scores_cast(const float* __restrict__ x,
        const float* __restrict__ wl, const float* __restrict__ wr,
        unsigned short* __restrict__ xb, float* __restrict__ el, float* __restrict__ er) {
    __shared__ float swl[R_REL * D], swr[R_REL * D];
    int t = threadIdx.x;
    for (int i = t; i < R_REL * D; i += 256) { swl[i] = wl[i]; swr[i] = wr[i]; }
    __syncthreads();
    int wv = t >> 6, lane = t & 63;
    int half = lane >> 5, q = lane & 31;           // q: float4 index within row
    long n = (long)blockIdx.x * 8 + wv * 2 + half; // N divisible by 8 -> no tail
    float4 v = ((const float4*)(x + n * D))[q];
    u16x4 ov;
    ov[0] = f2bf(v.x); ov[1] = f2bf(v.y); ov[2] = f2bf(v.z); ov[3] = f2bf(v.w);
    *(u16x4*)(xb + n * D + q * 4) = ov;
    float accl[R_REL], accr[R_REL];
    #pragma unroll
    for (int r = 0; r < R_REL; r++) {
        float4 w = ((const float4*)(swl + r * D))[q];
        accl[r] = v.x * w.x + v.y * w.y + v.z * w.z + v.w * w.w;
        float4 u = ((const float4*)(swr + r * D))[q];
        accr[r] = v.x * u.x + v.y * u.y + v.z * u.z + v.w * u.w;
    }
    #pragma unroll
    for (int r = 0; r < R_REL; r++) {
        #pragma unroll
        for (int d = 16; d >= 1; d >>= 1) {
            accl[r] += __shfl_xor(accl[r], d);
            accr[r] += __shfl_xor(accr[r], d);
        }
    }
    if (q == 0) {
        #pragma unroll
        for (int r = 0; r < R_REL; r++) {
            el[r * N_NODES + n] = accl[r];
            er[r * N_NODES + n] = accr[r];
        }
    }
}

// per-edge pass: relation-SEGMENTED bucket — one atomic on cnt4[r*N+dst],
// payload {src, p} into eb[dst*64 + r*16 + pos]. Segmenting makes the
// relation STATIC in k_aggproj's accumulation (fixes r14's 4x VALU bloat).
__global__ void k_scatter(const int* __restrict__ esrc, const int* __restrict__ edst,
                          const float* __restrict__ el, const float* __restrict__ er,
                          unsigned* __restrict__ cnt4, int2* __restrict__ eb) {
    int e = blockIdx.x * 256 + threadIdx.x;
    if (e >= E_EDGES) return;
    int r = blockIdx.y;
    int t = r * E_EDGES + e;
    int src = esrc[t], dst = edst[t];
    float lg = el[r * N_NODES + src] + er[r * N_NODES + dst];
    lg = lg > 0.f ? lg : NEG_SLOPE * lg;
    float p = __expf(lg);
    unsigned pos = atomicAdd(cnt4 + r * N_NODES + dst, 1u);
    if (pos < CAPR) eb[(long)dst * (R_REL * CAPR) + r * CAPR + pos] = make_int2(src, __float_as_int(p));
}

// Linearity aggregation+projection, relation-static Phase A:
// for each relation (STATIC loop): segment load -> one width-32 butterfly
// denominator -> validated 2-slot x 16-lane gather into ONE 8-reg accumulator
// (8 FMAs/edge, not r14's 32) -> flush to Z[rr] in LDS.
// Phase B (validated r14): out[16 dsts] = relu(sum_r Z_r @ W_r + btot).
__global__ __launch_bounds__(256) void k_aggproj(
        const int2* __restrict__ eb, const unsigned* __restrict__ cnt4,
        const unsigned short* __restrict__ xb, const unsigned short* __restrict__ Wt,
        const float* __restrict__ btot, float* __restrict__ out) {
    __shared__ unsigned short Z[R_REL][NB_DST][D + 8];
    int tid = threadIdx.x;
    int wv = tid >> 6, lane = tid & 63;
    int half = lane >> 5, l32 = lane & 31;
    int slot2 = l32 >> 4, c16 = lane & 15;
    int dbase = blockIdx.x * NB_DST;
    // ---- Phase A: each wave covers 4 dsts via 2 passes of the 2-dst scheme
    for (int ps = 0; ps < 2; ps++) {
        int dloc = wv * 4 + ps * 2 + half;
        int dst = dbase + dloc;
        const int2* bkt = eb + (long)dst * (R_REL * CAPR);
        #pragma unroll
        for (int rr = 0; rr < R_REL; rr++) {
            int2 m = bkt[rr * CAPR + (l32 & 15)];    // lanes 16-31 duplicate, masked dead
            unsigned num = cnt4[rr * N_NODES + dst];
            if (num > CAPR) num = CAPR;
            bool live = (unsigned)l32 < num;
            float pv = live ? __int_as_float(m.y) : 0.f;
            int srcid = m.x;
            // segment denominator: width-32 butterfly, full EXEC
            float dsum = pv;
            #pragma unroll
            for (int d = 1; d < 32; d <<= 1) dsum += __shfl_xor(dsum, d, 32);
            float alpha = live ? pv / dsum : 0.f;
            // gather: 2 slots x 16 lanes; UNIFORM trip count, shfl at full EXEC
            float az[8] = {0.f, 0.f, 0.f, 0.f, 0.f, 0.f, 0.f, 0.f};
            unsigned numo = __shfl_xor(num, 32);
            unsigned numMax = num > numo ? num : numo;   // wave-uniform
            unsigned iters = (numMax + 1) >> 1;
            for (unsigned i = 0; i < iters; i++) {
                unsigned q = slot2 + i * 2;              // q <= 15
                int srcl = half * 32 + (int)q;
                int rid = __shfl(srcid, srcl);
                float al = __shfl(alpha, srcl);
                if (q < num) {
                    u16x8 v = *(const u16x8*)(xb + (long)rid * D + c16 * 8);
                    #pragma unroll
                    for (int j = 0; j < 8; j++) az[j] += al * bf2f(v[j]);
                }
            }
            #pragma unroll
            for (int j = 0; j < 8; j++) az[j] += __shfl_xor(az[j], 16);
            if (slot2 == 0) {                            // lanes c16 of each half
                u16x8 zv;
                #pragma unroll
                for (int j = 0; j < 8; j++) zv[j] = f2bf(az[j]);
                *(u16x8*)(&Z[rr][dloc][c16 * 8]) = zv;
            }
        }
    }
    __syncthreads();
    // ---- Phase B (r14-validated): wave wv owns feature-tiles et = wv*2, wv*2+1
    int row16 = lane & 15, kgrp = lane >> 4;
    f32x4 acc0, acc1;
    acc0[0] = 0.f; acc0[1] = 0.f; acc0[2] = 0.f; acc0[3] = 0.f;
    acc1 = acc0;
    #pragma unroll
    for (int rr = 0; rr < R_REL; rr++) {
        const unsigned short* Wr = Wt + rr * D * D;
        #pragma unroll
        for (int kf = 0; kf < 4; kf++) {
            bf16x8v az = *(const bf16x8v*)(&Z[rr][row16][kf * 32 + kgrp * 8]);
            bf16x8v av0 = *(const bf16x8v*)(Wr + ((wv * 2) * 16 + row16) * D + kf * 32 + kgrp * 8);
            bf16x8v av1 = *(const bf16x8v*)(Wr + ((wv * 2 + 1) * 16 + row16) * D + kf * 32 + kgrp * 8);
            acc0 = __builtin_amdgcn_mfma_f32_16x16x32_bf16(av0, az, acc0, 0, 0, 0);
            acc1 = __builtin_amdgcn_mfma_f32_16x16x32_bf16(av1, az, acc1, 0, 0, 0);
        }
    }
    float* orow = out + (long)(dbase + row16) * D;
    int c0 = wv * 32 + kgrp * 4;
    const float4 b0 = *(const float4*)(btot + c0);
    const float4 b1 = *(const float4*)(btot + c0 + 16);
    float4 o0, o1;
    o0.x = acc0[0] + b0.x; o0.y = acc0[1] + b0.y; o0.z = acc0[2] + b0.z; o0.w = acc0[3] + b0.w;
    o1.x = acc1[0] + b1.x; o1.y = acc1[1] + b1.y; o1.z = acc1[2] + b1.z; o1.w = acc1[3] + b1.w;
    o0.x = o0.x > 0.f ? o0.x : 0.f; o0.y = o0.y > 0.f ? o0.y : 0.f;
    o0.z = o0.z > 0.f ? o0.z : 0.f; o0.w = o0.w > 0.f ? o0.w : 0.f;
    o1.x = o1.x > 0.f ? o1.x : 0.f; o1.y = o1.y > 0.f ? o1.y : 0.f;
    o1.z = o1.z > 0.f ? o1.z : 0.f; o1.w = o1.w > 0.f ? o1.w : 0.f;
    *(float4*)(orow + c0) = o0;
    *(float4*)(orow + c0 + 16) = o1;
}

extern "C" void kernel_launch(void* const* d_in, const int* in_sizes, int n_in,
                              void* d_out, int out_size, void* d_ws, size_t ws_size,
                              hipStream_t stream) {
    const float* x    = (const float*)d_in[0];
    const int*   esrc = (const int*)d_in[1];
    const int*   edst = (const int*)d_in[2];
    const float* Wsrc = (const float*)d_in[3];
    const float* Wdst = (const float*)d_in[4];
    const float* al   = (const float*)d_in[5];
    const float* ar   = (const float*)d_in[6];
    const float* gb   = (const float*)d_in[7];
    const float* hb   = (const float*)d_in[8];
    float* out = (float*)d_out;

    char* ws = (char*)d_ws;
    size_t o = 0;
    auto alloc = [&](size_t bytes) -> char* {
        char* r = ws + o; o += (bytes + 255) & ~(size_t)255; return r;
    };
    unsigned short* xb  = (unsigned short*)alloc((size_t)N_NODES * D * 2);   // 25.6 MB
    unsigned short* Wt  = (unsigned short*)alloc((size_t)R_REL * D * D * 2);
    float* el   = (float*)alloc((size_t)R_REL * N_NODES * 4);
    float* er   = (float*)alloc((size_t)R_REL * N_NODES * 4);
    float* wl   = (float*)alloc(R_REL * D * 4);
    float* wr   = (float*)alloc(R_REL * D * 4);
    float* btot = (float*)alloc(D * 4);
    unsigned* cnt4 = (unsigned*)alloc((size_t)R_REL * N_NODES * 4);          // 1.6 MB
    int2* eb = (int2*)alloc((size_t)N_NODES * R_REL * CAPR * 8);             // 51.2 MB
    // total ~82 MB

    int zblocks = (R_REL * N_NODES + 511) / 512;                 // 782
    k_prep2<<<dim3(33 + zblocks), dim3(512), 0, stream>>>(Wsrc, Wdst, al, ar, gb, hb,
                                                          wl, wr, btot, Wt, cnt4);
    k_scores_cast<<<dim3(N_NODES / 8), dim3(256), 0, stream>>>(x, wl, wr, xb, el, er);
    k_scatter<<<dim3(E_EDGES / 256, R_REL), dim3(256), 0, stream>>>(esrc, edst, el, er, cnt4, eb);
    k_aggproj<<<dim3(N_NODES / NB_DST), dim3(256), 0, stream>>>(eb, cnt4, xb, Wt, btot, out);
}

// Round 16
// 158.594 us; speedup vs baseline: 1.4171x; 1.4171x over previous
//
#include <hip/hip_runtime.h>
#include <hip/hip_bf16.h>

#define N_NODES 100000
#define R_REL 4
#define E_EDGES 160000
#define D 128
#define NEG_SLOPE 0.2f
#define CAP 32   // max edges per dst (all relations); Poisson(6.4): P(>32)*100K ~ 1e-10
#define GB 391   // gemm blocks per relation  = ceil(N/256)
#define SB 313   // scatter blocks per relation = ceil(E/512)

typedef unsigned short u16x8 __attribute__((ext_vector_type(8)));
typedef unsigned short u16x4 __attribute__((ext_vector_type(4)));
typedef __bf16 bf16x8v __attribute__((ext_vector_type(8)));
typedef float f32x4 __attribute__((ext_vector_type(4)));

__device__ inline unsigned short f2bf(float f) {
    unsigned u = __float_as_uint(f);
    return (unsigned short)((u + 0x7FFFu + ((u >> 16) & 1u)) >> 16);
}
__device__ inline float bf2f(unsigned short h) {
    return __uint_as_float(((unsigned)h) << 16);
}

// fused setup: block 0 = prep (wl/wr/btot), blocks 1-32 = W transpose+cast,
// blocks 33..228 = zero cnt.
__global__ __launch_bounds__(512) void k_prep2(const float* __restrict__ Wsrc,
        const float* __restrict__ Wdst, const float* __restrict__ al,
        const float* __restrict__ ar, const float* __restrict__ gb,
        const float* __restrict__ hb, float* __restrict__ wl,
        float* __restrict__ wr, float* __restrict__ btot,
        unsigned short* __restrict__ Wt, unsigned* __restrict__ cnt) {
    int b = blockIdx.x, t = threadIdx.x;
    if (b == 0) {
        int r = t >> 7, d = t & 127;
        const float* as = al + r * D;
        const float* ad = ar + r * D;
        const float* rs = Wsrc + (r * D + d) * D;
        const float* rd = Wdst + (r * D + d) * D;
        float s0 = 0.f, s1 = 0.f;
        for (int e = 0; e < D; e++) { s0 += rs[e] * as[e]; s1 += rd[e] * ad[e]; }
        wl[r * D + d] = s0; wr[r * D + d] = s1;
        if (t < D) {
            float bb = hb[t];
            for (int r2 = 0; r2 < R_REL; r2++) bb += gb[r2 * D + t];
            btot[t] = bb;
        }
    } else if (b <= 32) {
        int base = (b - 1) * 2048 + t;
        #pragma unroll
        for (int i = 0; i < 4; i++) {
            int idx = base + i * 512;
            int r = idx >> 14; int rem = idx & 16383; int e = rem >> 7; int k = rem & 127;
            Wt[idx] = f2bf(Wsrc[(r * D + k) * D + e]);
        }
    } else {
        int i = (b - 33) * 512 + t;
        if (i < N_NODES) cnt[i] = 0u;
    }
}

// fused: coalesced read of x (wave covers 2 rows), emits xb (bf16 cast),
// el[r,n] = x[n]·wl[r], er[r,n] = x[n]·wr[r] via shuffle reduce
__global__ __launch_bounds__(256) void k_scores_cast(const float* __restrict__ x,
        const float* __restrict__ wl, const float* __restrict__ wr,
        unsigned short* __restrict__ xb, float* __restrict__ el, float* __restrict__ er) {
    __shared__ float swl[R_REL * D], swr[R_REL * D];
    int t = threadIdx.x;
    for (int i = t; i < R_REL * D; i += 256) { swl[i] = wl[i]; swr[i] = wr[i]; }
    __syncthreads();
    int wv = t >> 6, lane = t & 63;
    int half = lane >> 5, q = lane & 31;           // q: float4 index within row
    long n = (long)blockIdx.x * 8 + wv * 2 + half; // N divisible by 8 -> no tail
    float4 v = ((const float4*)(x + n * D))[q];
    u16x4 ov;
    ov[0] = f2bf(v.x); ov[1] = f2bf(v.y); ov[2] = f2bf(v.z); ov[3] = f2bf(v.w);
    *(u16x4*)(xb + n * D + q * 4) = ov;
    float accl[R_REL], accr[R_REL];
    #pragma unroll
    for (int r = 0; r < R_REL; r++) {
        float4 w = ((const float4*)(swl + r * D))[q];
        accl[r] = v.x * w.x + v.y * w.y + v.z * w.z + v.w * w.w;
        float4 u = ((const float4*)(swr + r * D))[q];
        accr[r] = v.x * u.x + v.y * u.y + v.z * u.z + v.w * u.w;
    }
    #pragma unroll
    for (int r = 0; r < R_REL; r++) {
        #pragma unroll
        for (int d = 16; d >= 1; d >>= 1) {
            accl[r] += __shfl_xor(accl[r], d);
            accr[r] += __shfl_xor(accr[r], d);
        }
    }
    if (q == 0) {
        #pragma unroll
        for (int r = 0; r < R_REL; r++) {
            el[r * N_NODES + n] = accl[r];
            er[r * N_NODES + n] = accr[r];
        }
    }
}

// GEMM body (validated r7/r9/r10): one relation, 256 rows, W_r staged once, 1 barrier
__device__ __forceinline__ void gemm_body(int bx, int r, int tid,
        const unsigned short* __restrict__ xb, const unsigned short* __restrict__ Wt,
        unsigned short* __restrict__ hs, unsigned short (*B)[D + 8]) {
    int w = tid >> 6, l = tid & 63;
    int row16 = l & 15, kgrp = l >> 4;
    int n0 = bx * 256;
    bf16x8v a[2][4];
    int nr[2];
    #pragma unroll
    for (int rf = 0; rf < 2; rf++) {
        int nrow = n0 + w * 32 + rf * 16 + row16;
        nr[rf] = nrow;
        int nc = nrow < N_NODES ? nrow : N_NODES - 1;
        #pragma unroll
        for (int kf = 0; kf < 4; kf++)
            a[rf][kf] = *(const bf16x8v*)(xb + (long)nc * D + kf * 32 + kgrp * 8);
    }
    const unsigned short* Wr = Wt + r * D * D;
    #pragma unroll
    for (int it = 0; it < 4; it++) {
        int fi = (it * 512 + tid) * 8;
        *(u16x8*)(&B[fi >> 7][fi & 127]) = *(const u16x8*)(Wr + fi);
    }
    __syncthreads();
    f32x4 acc[2][8];
    #pragma unroll
    for (int rf = 0; rf < 2; rf++)
        #pragma unroll
        for (int et = 0; et < 8; et++) {
            acc[rf][et][0] = 0.f; acc[rf][et][1] = 0.f;
            acc[rf][et][2] = 0.f; acc[rf][et][3] = 0.f;
        }
    #pragma unroll
    for (int kf = 0; kf < 4; kf++) {
        #pragma unroll
        for (int et = 0; et < 8; et++) {
            bf16x8v av = *(const bf16x8v*)(&B[et * 16 + row16][kf * 32 + kgrp * 8]);
            acc[0][et] = __builtin_amdgcn_mfma_f32_16x16x32_bf16(av, a[0][kf], acc[0][et], 0, 0, 0);
            acc[1][et] = __builtin_amdgcn_mfma_f32_16x16x32_bf16(av, a[1][kf], acc[1][et], 0, 0, 0);
        }
    }
    #pragma unroll
    for (int rf = 0; rf < 2; rf++) {
        if (nr[rf] < N_NODES) {
            unsigned short* orow = hs + ((long)r * N_NODES + nr[rf]) * D;
            #pragma unroll
            for (int et = 0; et < 8; et++) {
                u16x4 o;
                o[0] = f2bf(acc[rf][et][0]); o[1] = f2bf(acc[rf][et][1]);
                o[2] = f2bf(acc[rf][et][2]); o[3] = f2bf(acc[rf][et][3]);
                *(u16x4*)(orow + et * 16 + kgrp * 4) = o;
            }
        }
    }
}

// scatter one edge (r10 order: gathers -> exp -> atomic -> bucket write)
__device__ __forceinline__ void scatter_edge(int e, int r,
        const int* __restrict__ esrc, const int* __restrict__ edst,
        const float* __restrict__ el, const float* __restrict__ er,
        unsigned* __restrict__ cnt, int2* __restrict__ eb) {
    int t = r * E_EDGES + e;
    int src = esrc[t], dst = edst[t];
    float lg = el[r * N_NODES + src] + er[r * N_NODES + dst];
    lg = lg > 0.f ? lg : NEG_SLOPE * lg;
    float p = __expf(lg);
    unsigned pos = atomicAdd(cnt + dst, 1u);
    if (pos < CAP) eb[dst * CAP + pos] = make_int2(r * N_NODES + src, __float_as_int(p));
}

// FUSED gemm+scatter — EXACT r10 mapping (best measured, 156.8us total):
// bx<GB -> GEMM tile, else scatter chunk. r11 wave-split, r12 interleave,
// r14/r15 linearity restructures all regressed.
__global__ __launch_bounds__(512) void k_gemm_scatter(
        const unsigned short* __restrict__ xb, const unsigned short* __restrict__ Wt,
        unsigned short* __restrict__ hs, const int* __restrict__ esrc,
        const int* __restrict__ edst, const float* __restrict__ el,
        const float* __restrict__ er, unsigned* __restrict__ cnt,
        int2* __restrict__ eb) {
    __shared__ unsigned short B[D][D + 8];
    int bx = blockIdx.x, r = blockIdx.y, tid = threadIdx.x;
    if (bx < GB) {
        gemm_body(bx, r, tid, xb, Wt, hs, B);
    } else {
        int e = (bx - GB) * 512 + tid;
        if (e < E_EDGES) scatter_edge(e, r, esrc, edst, el, er, cnt, eb);
    }
}

// fallback split kernels (used when ws too small for separate eb)
__global__ __launch_bounds__(512) void k_gemm_fb(const unsigned short* __restrict__ xb,
                                                 const unsigned short* __restrict__ Wt,
                                                 unsigned short* __restrict__ hs) {
    __shared__ unsigned short B[D][D + 8];
    gemm_body(blockIdx.x, blockIdx.y, threadIdx.x, xb, Wt, hs, B);
}

__global__ void k_scatter_fb(const int* __restrict__ esrc, const int* __restrict__ edst,
                             const float* __restrict__ el, const float* __restrict__ er,
                             unsigned* __restrict__ cnt, int2* __restrict__ eb) {
    int e = blockIdx.x * 256 + threadIdx.x;
    if (e >= E_EDGES) return;
    scatter_edge(e, blockIdx.y, esrc, edst, el, er, cnt, eb);
}

// TWO dsts per wave: lanes 0-31 own dstA, 32-63 own dstB (validated round 9).
__global__ __launch_bounds__(256) void k_agg(const int2* __restrict__ eb,
                                             const unsigned* __restrict__ cnt,
                                             const unsigned short* __restrict__ hs,
                                             const float* __restrict__ btot,
                                             float* __restrict__ out) {
    int wv = threadIdx.x >> 6, lane = threadIdx.x & 63;
    int half = lane >> 5, l32 = lane & 31;
    int dst = blockIdx.x * 8 + wv * 2 + half;    // N % 8 == 0 -> always valid
    unsigned num = cnt[dst];
    if (num > CAP) num = CAP;
    int rowid = 0, r = 0;
    float p = 0.f;
    if (l32 < num) {
        int2 m = eb[dst * CAP + l32];
        rowid = m.x;                             // rowid = r*N + src
        p = __int_as_float(m.y);
        r = (int)((unsigned)rowid / (unsigned)N_NODES);
    }
    // per-relation denominators: width-32 butterflies (stay within half), full EXEC
    float denom[R_REL];
    #pragma unroll
    for (int rr = 0; rr < R_REL; rr++) {
        float v = (r == rr) ? p : 0.f;
        #pragma unroll
        for (int d = 1; d < 32; d <<= 1) v += __shfl_xor(v, d, 32);
        denom[rr] = v;
    }
    float alpha = (l32 < num) ? p / denom[r] : 0.f;
    // gather-accumulate: per half, 2 slots x 16 lanes; UNIFORM trip count,
    // all shfl at full EXEC (shfl from exited lane undefined — r3/4 bug).
    int slot2 = l32 >> 4, c16 = lane & 15;
    float acc[8] = {0.f, 0.f, 0.f, 0.f, 0.f, 0.f, 0.f, 0.f};
    unsigned numo = __shfl_xor(num, 32);
    unsigned numMax = num > numo ? num : numo;
    unsigned iters = (numMax + 1) >> 1;
    for (unsigned i = 0; i < iters; i++) {
        unsigned q = slot2 + i * 2;              // q <= 31
        int srcl = half * 32 + (int)q;
        int rid = __shfl(rowid, srcl);
        float al = __shfl(alpha, srcl);
        if (q < num) {
            u16x8 v = *(const u16x8*)(hs + (long)rid * D + c16 * 8);
            #pragma unroll
            for (int j = 0; j < 8; j++) acc[j] += al * bf2f(v[j]);
        }
    }
    #pragma unroll
    for (int j = 0; j < 8; j++) acc[j] += __shfl_xor(acc[j], 16);
    if (slot2 == 0) {
        const float4 b0 = *(const float4*)(btot + c16 * 8);
        const float4 b1 = *(const float4*)(btot + c16 * 8 + 4);
        float4 o0, o1;
        o0.x = acc[0] + b0.x; o0.y = acc[1] + b0.y; o0.z = acc[2] + b0.z; o0.w = acc[3] + b0.w;
        o1.x = acc[4] + b1.x; o1.y = acc[5] + b1.y; o1.z = acc[6] + b1.z; o1.w = acc[7] + b1.w;
        o0.x = o0.x > 0.f ? o0.x : 0.f; o0.y = o0.y > 0.f ? o0.y : 0.f;
        o0.z = o0.z > 0.f ? o0.z : 0.f; o0.w = o0.w > 0.f ? o0.w : 0.f;
        o1.x = o1.x > 0.f ? o1.x : 0.f; o1.y = o1.y > 0.f ? o1.y : 0.f;
        o1.z = o1.z > 0.f ? o1.z : 0.f; o1.w = o1.w > 0.f ? o1.w : 0.f;
        *(float4*)(out + (long)dst * D + c16 * 8) = o0;
        *(float4*)(out + (long)dst * D + c16 * 8 + 4) = o1;
    }
}

extern "C" void kernel_launch(void* const* d_in, const int* in_sizes, int n_in,
                              void* d_out, int out_size, void* d_ws, size_t ws_size,
                              hipStream_t stream) {
    const float* x    = (const float*)d_in[0];
    const int*   esrc = (const int*)d_in[1];
    const int*   edst = (const int*)d_in[2];
    const float* Wsrc = (const float*)d_in[3];
    const float* Wdst = (const float*)d_in[4];
    const float* al   = (const float*)d_in[5];
    const float* ar   = (const float*)d_in[6];
    const float* gb   = (const float*)d_in[7];
    const float* hb   = (const float*)d_in[8];
    float* out = (float*)d_out;

    char* ws = (char*)d_ws;
    size_t o = 0;
    auto alloc = [&](size_t bytes) -> char* {
        char* r = ws + o; o += (bytes + 255) & ~(size_t)255; return r;
    };
    unsigned short* xb  = (unsigned short*)alloc((size_t)N_NODES * D * 2);   // 25.6 MB
    unsigned short* hsb = (unsigned short*)alloc((size_t)R_REL * N_NODES * D * 2);
    unsigned short* Wt  = (unsigned short*)alloc((size_t)R_REL * D * D * 2);
    float* el   = (float*)alloc((size_t)R_REL * N_NODES * 4);
    float* er   = (float*)alloc((size_t)R_REL * N_NODES * 4);
    float* wl   = (float*)alloc(R_REL * D * 4);
    float* wr   = (float*)alloc(R_REL * D * 4);
    float* btot = (float*)alloc(D * 4);
    unsigned* cnt = (unsigned*)alloc((size_t)N_NODES * 4);
    size_t base_end = o;
    size_t eb_bytes = (size_t)N_NODES * CAP * 8;                 // 25.6 MB
    // Separate eb enables gemm+scatter fusion (eb must not alias xb, which the
    // gemm role reads concurrently). Deterministic runtime guard: fall back to
    // the r9-proven alias + sequential dispatches if ws is too small.
    bool fused = (base_end + eb_bytes) <= ws_size;
    int2* eb = fused ? (int2*)alloc(eb_bytes) : (int2*)xb;

    int zblocks = (N_NODES + 511) / 512;                 // 196
    k_prep2<<<dim3(33 + zblocks), dim3(512), 0, stream>>>(Wsrc, Wdst, al, ar, gb, hb,
                                                          wl, wr, btot, Wt, cnt);
    k_scores_cast<<<dim3(N_NODES / 8), dim3(256), 0, stream>>>(x, wl, wr, xb, el, er);
    if (fused) {
        k_gemm_scatter<<<dim3(GB + SB, R_REL), dim3(512), 0, stream>>>(
            xb, Wt, hsb, esrc, edst, el, er, cnt, eb);
    } else {
        k_gemm_fb<<<dim3(GB, R_REL), dim3(512), 0, stream>>>(xb, Wt, hsb);
        k_scatter_fb<<<dim3((E_EDGES + 255) / 256, R_REL), dim3(256), 0, stream>>>(
            esrc, edst, el, er, cnt, eb);
    }
    k_agg<<<dim3(N_NODES / 8), dim3(256), 0, stream>>>(eb, cnt, hsb, btot, out);
}